// Round 9
// baseline (2364.354 us; speedup 1.0000x reference)
//
#include <hip/hip_runtime.h>
#include <hip/hip_bf16.h>

#define SEQn 70
#define Bn 128
#define En 512
#define Hn 1024
#define Vn 10000
#define VPADn 10240
#define Mn (SEQn*Bn)      // 8960
#define H3n (3*Hn)        // 3072
#define BHn (Bn*Hn)       // 131072
#define RBLK 64           // blocks per role

typedef __hip_bfloat16 bf16;
typedef __attribute__((ext_vector_type(8))) short short8;
typedef __attribute__((ext_vector_type(4))) float f32x4;

__device__ __forceinline__ bf16 f2bf(float x){ return __float2bfloat16(x); }
__device__ __forceinline__ float bf2f(bf16 x){ return __bfloat162float(x); }

__device__ __forceinline__ void gl_lds16(const void* g, void* l){
  __builtin_amdgcn_global_load_lds((const __attribute__((address_space(1))) unsigned int*)g,
                                   (__attribute__((address_space(3))) unsigned int*)l, 16, 0, 0);
}

// ---------------- small prep kernels ----------------

__global__ void cat3_w(const float* __restrict__ a, const float* __restrict__ b,
                       const float* __restrict__ c, bf16* __restrict__ d, int n){
  int i = blockIdx.x * 256 + threadIdx.x;
  if (i >= 3*n) return;
  const float* s = (i < n) ? a : ((i < 2*n) ? b : c);
  int off = (i < n) ? i : ((i < 2*n) ? i - n : i - 2*n);
  d[i] = f2bf(s[off]);
}

__global__ void cat3_f(const float* __restrict__ a, const float* __restrict__ b,
                       const float* __restrict__ c, float* __restrict__ d, int n){
  int i = blockIdx.x * 256 + threadIdx.x;
  if (i >= 3*n) return;
  d[i] = (i < n) ? a[i] : ((i < 2*n) ? b[i - n] : c[i - 2*n]);
}

__global__ void f2b_k(const float* __restrict__ s, bf16* __restrict__ d, int n){
  int i = blockIdx.x * 256 + threadIdx.x;
  if (i < n) d[i] = f2bf(s[i]);
}

__global__ void conv_outw(const float* __restrict__ s, bf16* __restrict__ d){
  long i = (long)blockIdx.x * 256 + threadIdx.x;
  if (i >= (long)VPADn * Hn) return;
  int row = (int)(i >> 10);
  d[i] = (row < Vn) ? f2bf(s[i]) : f2bf(0.f);
}

__global__ void embed_k(const int* __restrict__ idx, const float* __restrict__ eW,
                        bf16* __restrict__ out){
  const int sb = blockIdx.x;
  const int t = idx[sb];
  const float* s = eW + (long)t * En;
  bf16* d = out + (long)sb * En;
  for (int e = threadIdx.x; e < En; e += 256) d[e] = f2bf(s[e]);
}

// ---------------- GEMM: C[M,N] = A[M,K] * B[N,K]^T + bias ----------------

template<bool OB, bool NB>
__global__ __launch_bounds__(256)
void gemm_bt(const bf16* __restrict__ A, const bf16* __restrict__ Bm,
             const float* __restrict__ bias, void* __restrict__ C,
             int K, int ldc, int nvalid)
{
  __shared__ __align__(16) bf16 As[128*64];
  __shared__ __align__(16) bf16 Bs[128*64];
  const int tid = threadIdx.x;
  const int l = tid & 63, w = tid >> 6;
  const int lr = l & 15, lk = l >> 4;
  const int wm = (w >> 1) * 64, wn = (w & 1) * 64;
  const int mt = blockIdx.y, nt = blockIdx.x;
  const bf16* Ag = A + (long)mt * 128 * K;
  const bf16* Bg = Bm + (long)nt * 128 * K;

  f32x4 acc[4][4] = {};

  for (int kb = 0; kb < K; kb += 64) {
#pragma unroll
    for (int r = 0; r < 4; ++r) {
      const int u = r * 256 + tid;
      const int row = u >> 3, kus = (u & 7) ^ (row & 7);
      gl_lds16(Ag + (long)row * K + kb + kus * 8, (char*)As + (r * 256 + w * 64) * 16);
    }
#pragma unroll
    for (int r = 0; r < 4; ++r) {
      const int u = r * 256 + tid;
      const int row = u >> 3, kus = (u & 7) ^ (row & 7);
      gl_lds16(Bg + (long)row * K + kb + kus * 8, (char*)Bs + (r * 256 + w * 64) * 16);
    }
    __syncthreads();
#pragma unroll
    for (int kh = 0; kh < 2; ++kh) {
      const int ku = kh * 4 + lk;
      short8 af[4], bfv[4];
#pragma unroll
      for (int i = 0; i < 4; ++i) {
        const int ar = wm + i * 16 + lr;
        af[i]  = *(const short8*)((const char*)As + ar * 128 + ((ku ^ (ar & 7)) * 16));
        const int br = wn + i * 16 + lr;
        bfv[i] = *(const short8*)((const char*)Bs + br * 128 + ((ku ^ (br & 7)) * 16));
      }
#pragma unroll
      for (int i = 0; i < 4; ++i)
#pragma unroll
        for (int j = 0; j < 4; ++j)
          acc[i][j] = __builtin_amdgcn_mfma_f32_16x16x32_bf16(af[i], bfv[j], acc[i][j], 0, 0, 0);
    }
    __syncthreads();
  }

#pragma unroll
  for (int i = 0; i < 4; ++i) {
#pragma unroll
    for (int j = 0; j < 4; ++j) {
      const int col = nt * 128 + wn + j * 16 + lr;
      const bool cok = (!NB) || (col < nvalid);
      const float bv = cok ? bias[col] : 0.f;
      const int row = mt * 128 + wm + i * 16 + lk * 4;
      if (cok) {
#pragma unroll
        for (int r = 0; r < 4; ++r) {
          const float v = acc[i][j][r] + bv;
          if (OB) ((bf16*)C)[(long)(row + r) * ldc + col] = f2bf(v);
          else    ((float*)C)[(long)(row + r) * ldc + col] = v;
        }
      }
    }
  }
}

// ---------------- elastic persistent recurrence ----------------
// 192 blocks x 512 threads (8 waves). amdgpu_waves_per_eu(2,2) pins the
// allocator at 2 waves/EU -> 256-VGPR budget (launch_bounds can only set the
// MIN waves/EU; R7/R8's 128-VGPR spill came from the occupancy heuristic
// targeting 4/EU because 2 blocks fit by LDS). LDS is also bumped to 84KB so
// at most 1 block/CU fits -- a second, independent mechanism with same effect.
// Role = bid/64, nb = bid%64, cols nb*16..+15.
//   role 0: h0 recurrence; role 1: xg1 projection; role 2: h1 recurrence.
// Wave wid: mh = wid&1 (rows 0..63 / 64..127), kq = wid>>1 (K quarter).
// B-weights persist in registers (24 short8 = 96 VGPR); zero hot-loop LDS
// except one single-round cross-K reduction (6 zones x 12KB, 1 barrier).
// Sync: elastic per-role progress counters in MALL (relaxed agent atomics):
//   role0@t: C0>=64t ; role1@t: C0>=64(t+1) ; role2@t: C1>=64(t+1) && C2>=64t.
// Coherence: write-through agent stores for h/xg; plain consumer loads;
// agent loads for the role-2 xg alias. (Validated R4-R8.)

#define WAITGE(ptr, val)                                                       \
  while (__hip_atomic_load((ptr), __ATOMIC_RELAXED, __HIP_MEMORY_SCOPE_AGENT)  \
         < (val))                                                              \
    __builtin_amdgcn_s_sleep(1);

#define LDA(buf, kc)                                                           \
  _Pragma("unroll")                                                            \
  for (int rt = 0; rt < 4; ++rt)                                               \
    buf[rt] = *(const short8*)(pA[rt] + (kc) * 32);

#define MFM(buf, kc)                                                           \
  _Pragma("unroll")                                                            \
  for (int rt = 0; rt < 4; ++rt)                                               \
    _Pragma("unroll")                                                          \
    for (int g = 0; g < 3; ++g)                                                \
      acc[rt][g] = __builtin_amdgcn_mfma_f32_16x16x32_bf16(                    \
          buf[rt], bfr[g][kc], acc[rt][g], 0, 0, 0);

#define WRZ(zp)                                                                \
  _Pragma("unroll")                                                            \
  for (int rt = 0; rt < 4; ++rt)                                               \
    _Pragma("unroll")                                                          \
    for (int g = 0; g < 3; ++g)                                                \
      *(f32x4*)((zp) + (size_t)((rt * 3 + g) * 64 + lane) * 16) = acc[rt][g];

#define ADDZ(zp)                                                               \
  _Pragma("unroll")                                                            \
  for (int rt = 0; rt < 4; ++rt)                                               \
    _Pragma("unroll")                                                          \
    for (int g = 0; g < 3; ++g)                                                \
      acc[rt][g] += *(const f32x4*)((zp) + (size_t)((rt * 3 + g) * 64 + lane) * 16);

__global__ __launch_bounds__(512)
__attribute__((amdgpu_waves_per_eu(2, 2)))
void gru_rec(const bf16* __restrict__ Wh0, const bf16* __restrict__ Wi1,
             const bf16* __restrict__ Wh1, const float* __restrict__ b1,
             const float* __restrict__ hidden, bf16* __restrict__ xg,
             bf16* __restrict__ ys0, bf16* __restrict__ ys1,
             float* __restrict__ hT, unsigned* __restrict__ bar)
{
  __shared__ __align__(16) char smem[86016];   // 6 zones x 12KB used; sized to
                                               // forbid 2 blocks/CU (>80KB)

  const int tid = threadIdx.x;
  const int lane = tid & 63, wid = tid >> 6;
  const int lr = lane & 15, lk = lane >> 4;
  const int role = blockIdx.x >> 6, nb = blockIdx.x & 63;
  const int col0 = nb * 16;
  const int col = col0 + lr;
  const int mh = wid & 1, kq = wid >> 1;

  unsigned* c0 = bar;
  unsigned* c1 = bar + 64;
  unsigned* c2 = bar + 128;
  unsigned* own = (role == 0) ? c0 : ((role == 1) ? c1 : c2);

  // ---- persistent B fragments in registers (24 x short8 = 96 VGPR) ----
  const bf16* Wsrc = (role == 0) ? Wh0 : ((role == 1) ? Wi1 : Wh1);
  short8 bfr[3][8];
#pragma unroll
  for (int g = 0; g < 3; ++g)
#pragma unroll
    for (int kc = 0; kc < 8; ++kc)
      bfr[g][kc] = *(const short8*)(Wsrc + (size_t)(g * Hn + col0 + lr) * Hn
                                    + kq * 256 + kc * 32 + lk * 8);

  f32x4 hreg[4] = {};
  float bv[3] = {};
  if (role != 1) {
    if (kq == 0) {
      const float* hsrc = hidden + (role == 2 ? BHn : 0);
#pragma unroll
      for (int rt = 0; rt < 4; ++rt)
#pragma unroll
        for (int r = 0; r < 4; ++r)
          hreg[rt][r] = hsrc[(size_t)(mh * 64 + rt * 16 + lk * 4 + r) * Hn + col];
    }
  } else {
#pragma unroll
    for (int g = 0; g < 3; ++g) bv[g] = b1[g * Hn + col];
  }

  for (int t = 0; t < SEQn; ++t) {
    if (tid == 0) {
      if (role == 0)      { WAITGE(c0, 64u * (unsigned)t) }
      else if (role == 1) { WAITGE(c0, 64u * (unsigned)(t + 1)) }
      else { WAITGE(c1, 64u * (unsigned)(t + 1)) WAITGE(c2, 64u * (unsigned)t) }
    }
    __syncthreads();

    const bf16* Asrc = (role == 0) ? (ys0 + (size_t)t * BHn)
                     : (role == 1) ? (ys0 + (size_t)(t + 1) * BHn)
                                   : (ys1 + (size_t)t * BHn);
    const bf16* pA[4];
#pragma unroll
    for (int rt = 0; rt < 4; ++rt)
      pA[rt] = Asrc + (size_t)(mh * 64 + rt * 16 + lr) * Hn + kq * 256 + lk * 8;

    f32x4 acc[4][3] = {};
    short8 a0[4], a1[4];
    LDA(a0, 0) LDA(a1, 1)
    MFM(a0, 0) LDA(a0, 2)
    MFM(a1, 1) LDA(a1, 3)
    MFM(a0, 2) LDA(a0, 4)
    MFM(a1, 3) LDA(a1, 5)
    MFM(a0, 4) LDA(a0, 6)
    MFM(a1, 5) LDA(a1, 7)
    MFM(a0, 6)
    MFM(a1, 7)

    // ---- single-round cross-K reduction: kq 1..3 -> kq 0 ----
    if (kq != 0) { WRZ(smem + (size_t)((kq - 1) + 3 * mh) * 12288) }
    __syncthreads();
    if (kq == 0) {
      ADDZ(smem + (size_t)(3 * mh + 0) * 12288)
      ADDZ(smem + (size_t)(3 * mh + 1) * 12288)
      ADDZ(smem + (size_t)(3 * mh + 2) * 12288)
    }

    // ---- epilogue (kq==0 waves: wid 0 -> rows 0..63, wid 1 -> 64..127) ----
    if (kq == 0) {
      if (role == 1) {
#pragma unroll
        for (int rt = 0; rt < 4; ++rt)
#pragma unroll
          for (int g = 0; g < 3; ++g)
#pragma unroll
            for (int r = 0; r < 4; ++r) {
              const int row = mh * 64 + rt * 16 + lk * 4 + r;
              unsigned short v = __builtin_bit_cast(unsigned short,
                                                    f2bf(acc[rt][g][r] + bv[g]));
              __hip_atomic_store(
                  (unsigned short*)&xg[((size_t)t * Bn + row) * H3n + g * Hn + col],
                  v, __ATOMIC_RELAXED, __HIP_MEMORY_SCOPE_AGENT);
            }
      } else {
        const bf16* xsrc = xg + (size_t)t * Bn * (size_t)H3n;
        bf16* ydst = ((role == 0) ? ys0 : ys1) + (size_t)(t + 1) * BHn;
        float* hTd = hT + (role == 0 ? 0 : BHn);
#pragma unroll
        for (int rt = 0; rt < 4; ++rt)
#pragma unroll
          for (int r = 0; r < 4; ++r) {
            const int row = mh * 64 + rt * 16 + lk * 4 + r;
            const unsigned short* px =
                (const unsigned short*)(xsrc + (size_t)row * H3n + col);
            unsigned short uxr, uxz, uxh;
            if (role == 2) {
              uxr = __hip_atomic_load((unsigned short*)px, __ATOMIC_RELAXED, __HIP_MEMORY_SCOPE_AGENT);
              uxz = __hip_atomic_load((unsigned short*)(px + Hn), __ATOMIC_RELAXED, __HIP_MEMORY_SCOPE_AGENT);
              uxh = __hip_atomic_load((unsigned short*)(px + 2 * Hn), __ATOMIC_RELAXED, __HIP_MEMORY_SCOPE_AGENT);
            } else {
              uxr = px[0]; uxz = px[Hn]; uxh = px[2 * Hn];
            }
            const float xr = bf2f(__builtin_bit_cast(bf16, uxr));
            const float xz = bf2f(__builtin_bit_cast(bf16, uxz));
            const float xh = bf2f(__builtin_bit_cast(bf16, uxh));
            const float rg = 1.f / (1.f + __expf(-(xr + acc[rt][0][r])));
            const float zg = 1.f / (1.f + __expf(-(xz + acc[rt][1][r])));
            const float hc = tanhf(xh + rg * acc[rt][2][r]);
            const float hn = (1.f - zg) * hc + zg * hreg[rt][r];
            hreg[rt][r] = hn;
            unsigned short v = __builtin_bit_cast(unsigned short, f2bf(hn));
            __hip_atomic_store((unsigned short*)&ydst[(size_t)row * Hn + col],
                               v, __ATOMIC_RELAXED, __HIP_MEMORY_SCOPE_AGENT);
            if (t == SEQn - 1) hTd[(size_t)row * Hn + col] = hn;
          }
      }
    }
    __syncthreads();   // drains all waves' stores (vmcnt 0) before arrive
    if (tid == 0)
      __hip_atomic_fetch_add(own, 1u, __ATOMIC_RELAXED, __HIP_MEMORY_SCOPE_AGENT);
  }
}

// ---------------- launch ----------------

extern "C" void kernel_launch(void* const* d_in, const int* in_sizes, int n_in,
                              void* d_out, int out_size, void* d_ws, size_t ws_size,
                              hipStream_t stream)
{
  (void)in_sizes; (void)n_in; (void)out_size; (void)ws_size;
  const int*   inp    = (const int*)d_in[0];
  const float* hidden = (const float*)d_in[1];
  const float* embW   = (const float*)d_in[2];
  const float* outW   = (const float*)d_in[3];
  const float* outb   = (const float*)d_in[4];

  char* p = (char*)d_ws;
  auto take = [&](size_t n){ char* q = p; p += (n + 255) & ~(size_t)255; return q; };
  bf16*  l0Wi = (bf16*) take((size_t)H3n*En*2);
  bf16*  l0Wh = (bf16*) take((size_t)H3n*Hn*2);
  bf16*  l1Wi = (bf16*) take((size_t)H3n*Hn*2);
  bf16*  l1Wh = (bf16*) take((size_t)H3n*Hn*2);
  bf16*  oW   = (bf16*) take((size_t)VPADn*Hn*2);
  float* b0   = (float*)take((size_t)H3n*4);
  float* b1   = (float*)take((size_t)H3n*4);
  bf16*  emb  = (bf16*) take((size_t)Mn*En*2);
  bf16*  xg   = (bf16*) take((size_t)Mn*H3n*2);
  bf16*  ys0  = (bf16*) take((size_t)(SEQn+1)*BHn*2);
  bf16*  ys1  = (bf16*) take((size_t)(SEQn+1)*BHn*2);
  unsigned* bar = (unsigned*)take(4096);

  // weight/bias prep (bf16, gate-concatenated [r;z;h])
  cat3_w<<<dim3((3*Hn*En+255)/256),256,0,stream>>>((const float*)d_in[5],(const float*)d_in[6],(const float*)d_in[7], l0Wi, Hn*En);
  cat3_w<<<dim3((3*Hn*Hn+255)/256),256,0,stream>>>((const float*)d_in[8],(const float*)d_in[9],(const float*)d_in[10], l0Wh, Hn*Hn);
  cat3_w<<<dim3((3*Hn*Hn+255)/256),256,0,stream>>>((const float*)d_in[14],(const float*)d_in[15],(const float*)d_in[16], l1Wi, Hn*Hn);
  cat3_w<<<dim3((3*Hn*Hn+255)/256),256,0,stream>>>((const float*)d_in[17],(const float*)d_in[18],(const float*)d_in[19], l1Wh, Hn*Hn);
  conv_outw<<<dim3((unsigned)(((long)VPADn*Hn+255)/256)),256,0,stream>>>(outW, oW);
  cat3_f<<<dim3((H3n+255)/256),256,0,stream>>>((const float*)d_in[11],(const float*)d_in[12],(const float*)d_in[13], b0, Hn);
  cat3_f<<<dim3((H3n+255)/256),256,0,stream>>>((const float*)d_in[20],(const float*)d_in[21],(const float*)d_in[22], b1, Hn);
  f2b_k<<<dim3((BHn+255)/256),256,0,stream>>>(hidden, ys0, BHn);          // ys0 slot 0 = h0 init
  f2b_k<<<dim3((BHn+255)/256),256,0,stream>>>(hidden + BHn, ys1, BHn);    // ys1 slot 0 = h1 init
  embed_k<<<dim3(Mn),256,0,stream>>>(inp, embW, emb);
  (void)hipMemsetAsync(bar, 0, 4096, stream);

  // layer-0 input projection (xg slots hold xg0; role 1 overwrites per-stage)
  gemm_bt<true,false><<<dim3(H3n/128, Mn/128),256,0,stream>>>(emb, l0Wi, b0, xg, En, H3n, H3n);

  // both recurrences + layer-1 input projection, elastically pipelined
  float* hT = (float*)d_out + (size_t)SEQn * Bn * Vn;
  gru_rec<<<dim3(3*RBLK), 512, 0, stream>>>(l0Wh, l1Wi, l1Wh, b1, hidden,
                                            xg, ys0, ys1, hT, bar);

  // logits: ys1 slots 1..70 are h1[0..69]
  gemm_bt<false,true><<<dim3(VPADn/128, Mn/128),256,0,stream>>>(ys1 + BHn, oW, outb, d_out, Hn, Vn, Vn);
}

// Round 10
// 1767.009 us; speedup vs baseline: 1.3381x; 1.3381x over previous
//
#include <hip/hip_runtime.h>
#include <hip/hip_bf16.h>

#define SEQn 70
#define Bn 128
#define En 512
#define Hn 1024
#define Vn 10000
#define VPADn 10240
#define Mn (SEQn*Bn)      // 8960
#define H3n (3*Hn)        // 3072
#define BHn (Bn*Hn)       // 131072
#define RBLK 64           // blocks per role

typedef __hip_bfloat16 bf16;
typedef __attribute__((ext_vector_type(8))) short short8;
typedef __attribute__((ext_vector_type(4))) float f32x4;

__device__ __forceinline__ bf16 f2bf(float x){ return __float2bfloat16(x); }
__device__ __forceinline__ float bf2f(bf16 x){ return __bfloat162float(x); }

__device__ __forceinline__ void gl_lds16(const void* g, void* l){
  __builtin_amdgcn_global_load_lds((const __attribute__((address_space(1))) unsigned int*)g,
                                   (__attribute__((address_space(3))) unsigned int*)l, 16, 0, 0);
}

// ---------------- small prep kernels ----------------

__global__ void cat3_w(const float* __restrict__ a, const float* __restrict__ b,
                       const float* __restrict__ c, bf16* __restrict__ d, int n){
  int i = blockIdx.x * 256 + threadIdx.x;
  if (i >= 3*n) return;
  const float* s = (i < n) ? a : ((i < 2*n) ? b : c);
  int off = (i < n) ? i : ((i < 2*n) ? i - n : i - 2*n);
  d[i] = f2bf(s[off]);
}

__global__ void cat3_f(const float* __restrict__ a, const float* __restrict__ b,
                       const float* __restrict__ c, float* __restrict__ d, int n){
  int i = blockIdx.x * 256 + threadIdx.x;
  if (i >= 3*n) return;
  d[i] = (i < n) ? a[i] : ((i < 2*n) ? b[i - n] : c[i - 2*n]);
}

__global__ void f2b_k(const float* __restrict__ s, bf16* __restrict__ d, int n){
  int i = blockIdx.x * 256 + threadIdx.x;
  if (i < n) d[i] = f2bf(s[i]);
}

__global__ void conv_outw(const float* __restrict__ s, bf16* __restrict__ d){
  long i = (long)blockIdx.x * 256 + threadIdx.x;
  if (i >= (long)VPADn * Hn) return;
  int row = (int)(i >> 10);
  d[i] = (row < Vn) ? f2bf(s[i]) : f2bf(0.f);
}

__global__ void embed_k(const int* __restrict__ idx, const float* __restrict__ eW,
                        bf16* __restrict__ out){
  const int sb = blockIdx.x;
  const int t = idx[sb];
  const float* s = eW + (long)t * En;
  bf16* d = out + (long)sb * En;
  for (int e = threadIdx.x; e < En; e += 256) d[e] = f2bf(s[e]);
}

// ---------------- GEMM: C[M,N] = A[M,K] * B[N,K]^T + bias ----------------

template<bool OB, bool NB>
__global__ __launch_bounds__(256)
void gemm_bt(const bf16* __restrict__ A, const bf16* __restrict__ Bm,
             const float* __restrict__ bias, void* __restrict__ C,
             int K, int ldc, int nvalid)
{
  __shared__ __align__(16) bf16 As[128*64];
  __shared__ __align__(16) bf16 Bs[128*64];
  const int tid = threadIdx.x;
  const int l = tid & 63, w = tid >> 6;
  const int lr = l & 15, lk = l >> 4;
  const int wm = (w >> 1) * 64, wn = (w & 1) * 64;
  const int mt = blockIdx.y, nt = blockIdx.x;
  const bf16* Ag = A + (long)mt * 128 * K;
  const bf16* Bg = Bm + (long)nt * 128 * K;

  f32x4 acc[4][4] = {};

  for (int kb = 0; kb < K; kb += 64) {
#pragma unroll
    for (int r = 0; r < 4; ++r) {
      const int u = r * 256 + tid;
      const int row = u >> 3, kus = (u & 7) ^ (row & 7);
      gl_lds16(Ag + (long)row * K + kb + kus * 8, (char*)As + (r * 256 + w * 64) * 16);
    }
#pragma unroll
    for (int r = 0; r < 4; ++r) {
      const int u = r * 256 + tid;
      const int row = u >> 3, kus = (u & 7) ^ (row & 7);
      gl_lds16(Bg + (long)row * K + kb + kus * 8, (char*)Bs + (r * 256 + w * 64) * 16);
    }
    __syncthreads();
#pragma unroll
    for (int kh = 0; kh < 2; ++kh) {
      const int ku = kh * 4 + lk;
      short8 af[4], bfv[4];
#pragma unroll
      for (int i = 0; i < 4; ++i) {
        const int ar = wm + i * 16 + lr;
        af[i]  = *(const short8*)((const char*)As + ar * 128 + ((ku ^ (ar & 7)) * 16));
        const int br = wn + i * 16 + lr;
        bfv[i] = *(const short8*)((const char*)Bs + br * 128 + ((ku ^ (br & 7)) * 16));
      }
#pragma unroll
      for (int i = 0; i < 4; ++i)
#pragma unroll
        for (int j = 0; j < 4; ++j)
          acc[i][j] = __builtin_amdgcn_mfma_f32_16x16x32_bf16(af[i], bfv[j], acc[i][j], 0, 0, 0);
    }
    __syncthreads();
  }

#pragma unroll
  for (int i = 0; i < 4; ++i) {
#pragma unroll
    for (int j = 0; j < 4; ++j) {
      const int col = nt * 128 + wn + j * 16 + lr;
      const bool cok = (!NB) || (col < nvalid);
      const float bv = cok ? bias[col] : 0.f;
      const int row = mt * 128 + wm + i * 16 + lk * 4;
      if (cok) {
#pragma unroll
        for (int r = 0; r < 4; ++r) {
          const float v = acc[i][j][r] + bv;
          if (OB) ((bf16*)C)[(long)(row + r) * ldc + col] = f2bf(v);
          else    ((float*)C)[(long)(row + r) * ldc + col] = v;
        }
      }
    }
  }
}

// ---------------- elastic persistent recurrence ----------------
// 192 blocks x 512 threads (8 waves = mh(2) x kq(4)); 1 block/CU (144KB LDS)
// -> 2 waves/SIMD of TLP. Role = bid/64, nb = bid%64, cols nb*16..+15.
//   role 0: h0 recurrence; role 1: xg1 projection; role 2: h1 recurrence.
// B-weights live in LDS in MFMA-FRAGMENT ORDER (R6-verified conflict-free:
// every ds_read_b128 is base+lane*16): 96KB. Arch-VGPR working set ~100
// (A dbuf 32 + B dbuf 24 + misc; acc -> AGPRs) -- fits the 128 budget this
// toolchain pins 512-thread kernels to (R7-R9 evidence), so NO SPILL.
// Cross-kq reduction: 2 rounds via 4 x 12KB LDS zones.
// Sync: elastic per-role progress counters in MALL (relaxed agent atomics):
//   role0@t: C0>=64t ; role1@t: C0>=64(t+1) ; role2@t: C1>=64(t+1) && C2>=64t.
// Coherence: write-through agent stores for h/xg; plain consumer loads;
// agent loads for the role-2 xg alias. (Validated R4-R9.)

#define WAITGE(ptr, val)                                                       \
  while (__hip_atomic_load((ptr), __ATOMIC_RELAXED, __HIP_MEMORY_SCOPE_AGENT)  \
         < (val))                                                              \
    __builtin_amdgcn_s_sleep(1);

#define LDB(bb, j)                                                             \
  _Pragma("unroll")                                                            \
  for (int g = 0; g < 3; ++g)                                                  \
    bb[g] = *(const short8*)(smem +                                            \
        ((size_t)((g * 32 + kq * 8 + (j)) * 64 + lane)) * 16);

#define LDA(aa, j)                                                             \
  _Pragma("unroll")                                                            \
  for (int rt = 0; rt < 4; ++rt)                                               \
    aa[rt] = *(const short8*)(pA[rt] + (j) * 32);

#define MF(aa, bb)                                                             \
  _Pragma("unroll")                                                            \
  for (int rt = 0; rt < 4; ++rt)                                               \
    _Pragma("unroll")                                                          \
    for (int g = 0; g < 3; ++g)                                                \
      acc[rt][g] = __builtin_amdgcn_mfma_f32_16x16x32_bf16(                    \
          aa[rt], bb[g], acc[rt][g], 0, 0, 0);

#define WRZ(zp)                                                                \
  _Pragma("unroll")                                                            \
  for (int rt = 0; rt < 4; ++rt)                                               \
    _Pragma("unroll")                                                          \
    for (int g = 0; g < 3; ++g)                                                \
      *(f32x4*)((zp) + (size_t)((rt * 3 + g) * 64 + lane) * 16) = acc[rt][g];

#define ADDZ(zp)                                                               \
  _Pragma("unroll")                                                            \
  for (int rt = 0; rt < 4; ++rt)                                               \
    _Pragma("unroll")                                                          \
    for (int g = 0; g < 3; ++g)                                                \
      acc[rt][g] += *(const f32x4*)((zp) + (size_t)((rt * 3 + g) * 64 + lane) * 16);

__global__ __launch_bounds__(512)
void gru_rec(const bf16* __restrict__ Wh0, const bf16* __restrict__ Wi1,
             const bf16* __restrict__ Wh1, const float* __restrict__ b1,
             const float* __restrict__ hidden, bf16* __restrict__ xg,
             bf16* __restrict__ ys0, bf16* __restrict__ ys1,
             float* __restrict__ hT, unsigned* __restrict__ bar)
{
  __shared__ __align__(16) char smem[147456];  // 96KB B frags + 4 x 12KB zones

  const int tid = threadIdx.x;
  const int lane = tid & 63, wid = tid >> 6;
  const int lr = lane & 15, lk = lane >> 4;
  const int role = blockIdx.x >> 6, nb = blockIdx.x & 63;
  const int col0 = nb * 16;
  const int col = col0 + lr;
  const int mh = wid & 1, kq = wid >> 1;

  unsigned* c0 = bar;
  unsigned* c1 = bar + 64;
  unsigned* c2 = bar + 128;
  unsigned* own = (role == 0) ? c0 : ((role == 1) ? c1 : c2);

  // ---- preload B into LDS in MFMA-fragment order (R6-verified layout) ----
  // 16B unit (g*32+c)*64+l holds W[g*1024+col0+(l&15)][c*32+(l>>4)*8 ..+8]
  const bf16* Wsrc = (role == 0) ? Wh0 : ((role == 1) ? Wi1 : Wh1);
#pragma unroll
  for (int it = 0; it < 12; ++it) {
    const int u0 = it * 512 + (tid & ~63);     // wave-uniform LDS unit base
    const int u  = u0 + lane;
    const int g  = u >> 11, c = (u >> 6) & 31, l = u & 63;
    gl_lds16(Wsrc + ((size_t)(g * Hn + col0 + (l & 15))) * Hn + c * 32 + (l >> 4) * 8,
             smem + (size_t)u0 * 16);
  }

  f32x4 hreg[4] = {};
  float bv[3] = {};
  if (role != 1) {
    if (kq == 0) {
      const float* hsrc = hidden + (role == 2 ? BHn : 0);
#pragma unroll
      for (int rt = 0; rt < 4; ++rt)
#pragma unroll
        for (int r = 0; r < 4; ++r)
          hreg[rt][r] = hsrc[(size_t)(mh * 64 + rt * 16 + lk * 4 + r) * Hn + col];
    }
  } else {
#pragma unroll
    for (int g = 0; g < 3; ++g) bv[g] = b1[g * Hn + col];
  }
  asm volatile("s_waitcnt vmcnt(0)" ::: "memory");
  __syncthreads();

  char* zA = smem + 98304 + (size_t)(mh * 2 + 0) * 12288;
  char* zB = smem + 98304 + (size_t)(mh * 2 + 1) * 12288;

  for (int t = 0; t < SEQn; ++t) {
    if (tid == 0) {
      if (role == 0)      { WAITGE(c0, 64u * (unsigned)t) }
      else if (role == 1) { WAITGE(c0, 64u * (unsigned)(t + 1)) }
      else { WAITGE(c1, 64u * (unsigned)(t + 1)) WAITGE(c2, 64u * (unsigned)t) }
    }
    __syncthreads();

    const bf16* Asrc = (role == 0) ? (ys0 + (size_t)t * BHn)
                     : (role == 1) ? (ys0 + (size_t)(t + 1) * BHn)
                                   : (ys1 + (size_t)t * BHn);
    const bf16* pA[4];
#pragma unroll
    for (int rt = 0; rt < 4; ++rt)
      pA[rt] = Asrc + (size_t)(mh * 64 + rt * 16 + lr) * Hn + kq * 256 + lk * 8;

    f32x4 acc[4][3] = {};
    short8 a0[4], a1[4], b0[3], b1f[3];
    LDB(b0, 0)  LDA(a0, 0)
    LDB(b1f, 1) LDA(a1, 1)
    MF(a0, b0)  LDB(b0, 2)  LDA(a0, 2)
    MF(a1, b1f) LDB(b1f, 3) LDA(a1, 3)
    MF(a0, b0)  LDB(b0, 4)  LDA(a0, 4)
    MF(a1, b1f) LDB(b1f, 5) LDA(a1, 5)
    MF(a0, b0)  LDB(b0, 6)  LDA(a0, 6)
    MF(a1, b1f) LDB(b1f, 7) LDA(a1, 7)
    MF(a0, b0)
    MF(a1, b1f)

    // ---- cross-kq reduction, 2 rounds via 4 zones ----
    if (kq == 1) { WRZ(zA) }
    if (kq == 3) { WRZ(zB) }
    __syncthreads();
    if (kq == 0) { ADDZ(zA) }
    if (kq == 2) { ADDZ(zB) WRZ(zB) }
    __syncthreads();
    if (kq == 0) { ADDZ(zB) }

    // ---- epilogue (kq==0 waves: mh 0 -> rows 0..63, mh 1 -> 64..127) ----
    if (kq == 0) {
      if (role == 1) {
#pragma unroll
        for (int rt = 0; rt < 4; ++rt)
#pragma unroll
          for (int g = 0; g < 3; ++g)
#pragma unroll
            for (int r = 0; r < 4; ++r) {
              const int row = mh * 64 + rt * 16 + lk * 4 + r;
              unsigned short v = __builtin_bit_cast(unsigned short,
                                                    f2bf(acc[rt][g][r] + bv[g]));
              __hip_atomic_store(
                  (unsigned short*)&xg[((size_t)t * Bn + row) * H3n + g * Hn + col],
                  v, __ATOMIC_RELAXED, __HIP_MEMORY_SCOPE_AGENT);
            }
      } else {
        const bf16* xsrc = xg + (size_t)t * Bn * (size_t)H3n;
        bf16* ydst = ((role == 0) ? ys0 : ys1) + (size_t)(t + 1) * BHn;
        float* hTd = hT + (role == 0 ? 0 : BHn);
#pragma unroll
        for (int rt = 0; rt < 4; ++rt)
#pragma unroll
          for (int r = 0; r < 4; ++r) {
            const int row = mh * 64 + rt * 16 + lk * 4 + r;
            const unsigned short* px =
                (const unsigned short*)(xsrc + (size_t)row * H3n + col);
            unsigned short uxr, uxz, uxh;
            if (role == 2) {
              uxr = __hip_atomic_load((unsigned short*)px, __ATOMIC_RELAXED, __HIP_MEMORY_SCOPE_AGENT);
              uxz = __hip_atomic_load((unsigned short*)(px + Hn), __ATOMIC_RELAXED, __HIP_MEMORY_SCOPE_AGENT);
              uxh = __hip_atomic_load((unsigned short*)(px + 2 * Hn), __ATOMIC_RELAXED, __HIP_MEMORY_SCOPE_AGENT);
            } else {
              uxr = px[0]; uxz = px[Hn]; uxh = px[2 * Hn];
            }
            const float xr = bf2f(__builtin_bit_cast(bf16, uxr));
            const float xz = bf2f(__builtin_bit_cast(bf16, uxz));
            const float xh = bf2f(__builtin_bit_cast(bf16, uxh));
            const float rg = 1.f / (1.f + __expf(-(xr + acc[rt][0][r])));
            const float zg = 1.f / (1.f + __expf(-(xz + acc[rt][1][r])));
            const float hc = tanhf(xh + rg * acc[rt][2][r]);
            const float hn = (1.f - zg) * hc + zg * hreg[rt][r];
            hreg[rt][r] = hn;
            unsigned short v = __builtin_bit_cast(unsigned short, f2bf(hn));
            __hip_atomic_store((unsigned short*)&ydst[(size_t)row * Hn + col],
                               v, __ATOMIC_RELAXED, __HIP_MEMORY_SCOPE_AGENT);
            if (t == SEQn - 1) hTd[(size_t)row * Hn + col] = hn;
          }
      }
    }
    __syncthreads();   // drains all waves' stores (vmcnt 0) before arrive
    if (tid == 0)
      __hip_atomic_fetch_add(own, 1u, __ATOMIC_RELAXED, __HIP_MEMORY_SCOPE_AGENT);
  }
}

// ---------------- launch ----------------

extern "C" void kernel_launch(void* const* d_in, const int* in_sizes, int n_in,
                              void* d_out, int out_size, void* d_ws, size_t ws_size,
                              hipStream_t stream)
{
  (void)in_sizes; (void)n_in; (void)out_size; (void)ws_size;
  const int*   inp    = (const int*)d_in[0];
  const float* hidden = (const float*)d_in[1];
  const float* embW   = (const float*)d_in[2];
  const float* outW   = (const float*)d_in[3];
  const float* outb   = (const float*)d_in[4];

  char* p = (char*)d_ws;
  auto take = [&](size_t n){ char* q = p; p += (n + 255) & ~(size_t)255; return q; };
  bf16*  l0Wi = (bf16*) take((size_t)H3n*En*2);
  bf16*  l0Wh = (bf16*) take((size_t)H3n*Hn*2);
  bf16*  l1Wi = (bf16*) take((size_t)H3n*Hn*2);
  bf16*  l1Wh = (bf16*) take((size_t)H3n*Hn*2);
  bf16*  oW   = (bf16*) take((size_t)VPADn*Hn*2);
  float* b0   = (float*)take((size_t)H3n*4);
  float* b1   = (float*)take((size_t)H3n*4);
  bf16*  emb  = (bf16*) take((size_t)Mn*En*2);
  bf16*  xg   = (bf16*) take((size_t)Mn*H3n*2);
  bf16*  ys0  = (bf16*) take((size_t)(SEQn+1)*BHn*2);
  bf16*  ys1  = (bf16*) take((size_t)(SEQn+1)*BHn*2);
  unsigned* bar = (unsigned*)take(4096);

  // weight/bias prep (bf16, gate-concatenated [r;z;h])
  cat3_w<<<dim3((3*Hn*En+255)/256),256,0,stream>>>((const float*)d_in[5],(const float*)d_in[6],(const float*)d_in[7], l0Wi, Hn*En);
  cat3_w<<<dim3((3*Hn*Hn+255)/256),256,0,stream>>>((const float*)d_in[8],(const float*)d_in[9],(const float*)d_in[10], l0Wh, Hn*Hn);
  cat3_w<<<dim3((3*Hn*Hn+255)/256),256,0,stream>>>((const float*)d_in[14],(const float*)d_in[15],(const float*)d_in[16], l1Wi, Hn*Hn);
  cat3_w<<<dim3((3*Hn*Hn+255)/256),256,0,stream>>>((const float*)d_in[17],(const float*)d_in[18],(const float*)d_in[19], l1Wh, Hn*Hn);
  conv_outw<<<dim3((unsigned)(((long)VPADn*Hn+255)/256)),256,0,stream>>>(outW, oW);
  cat3_f<<<dim3((H3n+255)/256),256,0,stream>>>((const float*)d_in[11],(const float*)d_in[12],(const float*)d_in[13], b0, Hn);
  cat3_f<<<dim3((H3n+255)/256),256,0,stream>>>((const float*)d_in[20],(const float*)d_in[21],(const float*)d_in[22], b1, Hn);
  f2b_k<<<dim3((BHn+255)/256),256,0,stream>>>(hidden, ys0, BHn);          // ys0 slot 0 = h0 init
  f2b_k<<<dim3((BHn+255)/256),256,0,stream>>>(hidden + BHn, ys1, BHn);    // ys1 slot 0 = h1 init
  embed_k<<<dim3(Mn),256,0,stream>>>(inp, embW, emb);
  (void)hipMemsetAsync(bar, 0, 4096, stream);

  // layer-0 input projection (xg slots hold xg0; role 1 overwrites per-stage)
  gemm_bt<true,false><<<dim3(H3n/128, Mn/128),256,0,stream>>>(emb, l0Wi, b0, xg, En, H3n, H3n);

  // both recurrences + layer-1 input projection, elastically pipelined
  float* hT = (float*)d_out + (size_t)SEQn * Bn * Vn;
  gru_rec<<<dim3(3*RBLK), 512, 0, stream>>>(l0Wh, l1Wi, l1Wh, b1, hidden,
                                            xg, ys0, ys1, hT, bar);

  // logits: ys1 slots 1..70 are h1[0..69]
  gemm_bt<false,true><<<dim3(VPADn/128, Mn/128),256,0,stream>>>(ys1 + BHn, oW, outb, d_out, Hn, Vn, Vn);
}

// Round 12
// 1600.069 us; speedup vs baseline: 1.4777x; 1.1043x over previous
//
#include <hip/hip_runtime.h>
#include <hip/hip_bf16.h>

#define SEQn 70
#define Bn 128
#define En 512
#define Hn 1024
#define Vn 10000
#define VPADn 10240
#define Mn (SEQn*Bn)      // 8960
#define H3n (3*Hn)        // 3072
#define BHn (Bn*Hn)       // 131072
#define NBLK 192

typedef __hip_bfloat16 bf16;
typedef __attribute__((ext_vector_type(8))) short short8;
typedef __attribute__((ext_vector_type(4))) float f32x4;

__device__ __forceinline__ bf16 f2bf(float x){ return __float2bfloat16(x); }
__device__ __forceinline__ float bf2f(bf16 x){ return __bfloat162float(x); }

__device__ __forceinline__ void gl_lds16(const void* g, void* l){
  __builtin_amdgcn_global_load_lds((const __attribute__((address_space(1))) unsigned int*)g,
                                   (__attribute__((address_space(3))) unsigned int*)l, 16, 0, 0);
}

// ---------------- small prep kernels ----------------

__global__ void cat3_w(const float* __restrict__ a, const float* __restrict__ b,
                       const float* __restrict__ c, bf16* __restrict__ d, int n){
  int i = blockIdx.x * 256 + threadIdx.x;
  if (i >= 3*n) return;
  const float* s = (i < n) ? a : ((i < 2*n) ? b : c);
  int off = (i < n) ? i : ((i < 2*n) ? i - n : i - 2*n);
  d[i] = f2bf(s[off]);
}

__global__ void cat3_f(const float* __restrict__ a, const float* __restrict__ b,
                       const float* __restrict__ c, float* __restrict__ d, int n){
  int i = blockIdx.x * 256 + threadIdx.x;
  if (i >= 3*n) return;
  d[i] = (i < n) ? a[i] : ((i < 2*n) ? b[i - n] : c[i - 2*n]);
}

__global__ void f2b_k(const float* __restrict__ s, bf16* __restrict__ d, int n){
  int i = blockIdx.x * 256 + threadIdx.x;
  if (i < n) d[i] = f2bf(s[i]);
}

__global__ void conv_outw(const float* __restrict__ s, bf16* __restrict__ d){
  long i = (long)blockIdx.x * 256 + threadIdx.x;
  if (i >= (long)VPADn * Hn) return;
  int row = (int)(i >> 10);
  d[i] = (row < Vn) ? f2bf(s[i]) : f2bf(0.f);
}

__global__ void embed_k(const int* __restrict__ idx, const float* __restrict__ eW,
                        bf16* __restrict__ out){
  const int sb = blockIdx.x;
  const int t = idx[sb];
  const float* s = eW + (long)t * En;
  bf16* d = out + (long)sb * En;
  for (int e = threadIdx.x; e < En; e += 256) d[e] = f2bf(s[e]);
}

// ---------------- GEMM: C[M,N] = A[M,K] * B[N,K]^T + bias ----------------

template<bool OB, bool NB>
__global__ __launch_bounds__(256)
void gemm_bt(const bf16* __restrict__ A, const bf16* __restrict__ Bm,
             const float* __restrict__ bias, void* __restrict__ C,
             int K, int ldc, int nvalid)
{
  __shared__ __align__(16) bf16 As[128*64];
  __shared__ __align__(16) bf16 Bs[128*64];
  const int tid = threadIdx.x;
  const int l = tid & 63, w = tid >> 6;
  const int lr = l & 15, lk = l >> 4;
  const int wm = (w >> 1) * 64, wn = (w & 1) * 64;
  const int mt = blockIdx.y, nt = blockIdx.x;
  const bf16* Ag = A + (long)mt * 128 * K;
  const bf16* Bg = Bm + (long)nt * 128 * K;

  f32x4 acc[4][4] = {};

  for (int kb = 0; kb < K; kb += 64) {
#pragma unroll
    for (int r = 0; r < 4; ++r) {
      const int u = r * 256 + tid;
      const int row = u >> 3, kus = (u & 7) ^ (row & 7);
      gl_lds16(Ag + (long)row * K + kb + kus * 8, (char*)As + (r * 256 + w * 64) * 16);
    }
#pragma unroll
    for (int r = 0; r < 4; ++r) {
      const int u = r * 256 + tid;
      const int row = u >> 3, kus = (u & 7) ^ (row & 7);
      gl_lds16(Bg + (long)row * K + kb + kus * 8, (char*)Bs + (r * 256 + w * 64) * 16);
    }
    __syncthreads();
#pragma unroll
    for (int kh = 0; kh < 2; ++kh) {
      const int ku = kh * 4 + lk;
      short8 af[4], bfv[4];
#pragma unroll
      for (int i = 0; i < 4; ++i) {
        const int ar = wm + i * 16 + lr;
        af[i]  = *(const short8*)((const char*)As + ar * 128 + ((ku ^ (ar & 7)) * 16));
        const int br = wn + i * 16 + lr;
        bfv[i] = *(const short8*)((const char*)Bs + br * 128 + ((ku ^ (br & 7)) * 16));
      }
#pragma unroll
      for (int i = 0; i < 4; ++i)
#pragma unroll
        for (int j = 0; j < 4; ++j)
          acc[i][j] = __builtin_amdgcn_mfma_f32_16x16x32_bf16(af[i], bfv[j], acc[i][j], 0, 0, 0);
    }
    __syncthreads();
  }

#pragma unroll
  for (int i = 0; i < 4; ++i) {
#pragma unroll
    for (int j = 0; j < 4; ++j) {
      const int col = nt * 128 + wn + j * 16 + lr;
      const bool cok = (!NB) || (col < nvalid);
      const float bv = cok ? bias[col] : 0.f;
      const int row = mt * 128 + wm + i * 16 + lk * 4;
      if (cok) {
#pragma unroll
        for (int r = 0; r < 4; ++r) {
          const float v = acc[i][j][r] + bv;
          if (OB) ((bf16*)C)[(long)(row + r) * ldc + col] = f2bf(v);
          else    ((float*)C)[(long)(row + r) * ldc + col] = v;
        }
      }
    }
  }
}

// ---------------- persistent pipelined GRU ----------------
// 192 blocks x 512 threads (8 waves = mh(2) x kq(4)); 1 block/CU (144KB LDS).
// Stage s: role0 computes h0[t=s]; role1 xg1[t=s-1]; role2 h1[t=s-2].
// Compute core = R10 (counter-verified: 124 VGPR no spill, fragment-order
// LDS B reads conflict-free, A global->reg 2-deep dbuf, 2-round cross-kq
// reduction in 4 x 12KB zones).
// Sync = R6 barrier VERBATIM (ran 72 stages correctly): arrive via XCD-local
// L2 RMW, XCD-last leader adds count to MALL counter, device-last sets MALL
// flag, ALL tid0s poll the MALL flag with AGENT-scope loads.
// (R11's "local release cascade" deadlocked: peers polled a cross-workgroup
// flag with WORKGROUP-scope loads, which may be served stale from L1
// forever. Rule: cross-block spin flags need agent-scope loads or
// L2-executing atomic RMWs.)
// Coherence: write-through agent stores for h/xg; plain consumer loads;
// agent loads for the role-2 xg alias. (Validated R4-R10.)

#define LDB(bb, j)                                                             \
  _Pragma("unroll")                                                            \
  for (int g = 0; g < 3; ++g)                                                  \
    bb[g] = *(const short8*)(smem +                                            \
        ((size_t)((g * 32 + kq * 8 + (j)) * 64 + lane)) * 16);

#define LDA(aa, j)                                                             \
  _Pragma("unroll")                                                            \
  for (int rt = 0; rt < 4; ++rt)                                               \
    aa[rt] = *(const short8*)(pA[rt] + (j) * 32);

#define MF(aa, bb)                                                             \
  _Pragma("unroll")                                                            \
  for (int rt = 0; rt < 4; ++rt)                                               \
    _Pragma("unroll")                                                          \
    for (int g = 0; g < 3; ++g)                                                \
      acc[rt][g] = __builtin_amdgcn_mfma_f32_16x16x32_bf16(                    \
          aa[rt], bb[g], acc[rt][g], 0, 0, 0);

#define WRZ(zp)                                                                \
  _Pragma("unroll")                                                            \
  for (int rt = 0; rt < 4; ++rt)                                               \
    _Pragma("unroll")                                                          \
    for (int g = 0; g < 3; ++g)                                                \
      *(f32x4*)((zp) + (size_t)((rt * 3 + g) * 64 + lane) * 16) = acc[rt][g];

#define ADDZ(zp)                                                               \
  _Pragma("unroll")                                                            \
  for (int rt = 0; rt < 4; ++rt)                                               \
    _Pragma("unroll")                                                          \
    for (int g = 0; g < 3; ++g)                                                \
      acc[rt][g] += *(const f32x4*)((zp) + (size_t)((rt * 3 + g) * 64 + lane) * 16);

__global__ __launch_bounds__(512)
void gru_persist(const bf16* __restrict__ Wh0, const bf16* __restrict__ Wi1,
                 const bf16* __restrict__ Wh1, const float* __restrict__ b1,
                 const float* __restrict__ hidden, bf16* __restrict__ xg,
                 bf16* __restrict__ ys0, bf16* __restrict__ ys1,
                 float* __restrict__ hT, unsigned* __restrict__ bar)
{
  __shared__ __align__(16) char smem[147456];  // 96KB B frags + 4 x 12KB zones

  const int tid = threadIdx.x;
  const int lane = tid & 63, wid = tid >> 6;
  const int lr = lane & 15, lk = lane >> 4;
  const int role = blockIdx.x >> 6, nb = blockIdx.x & 63;
  const int col0 = nb * 16;
  const int col = col0 + lr;
  const int mh = wid & 1, kq = wid >> 1;

  unsigned myxcd;
  asm("s_getreg_b32 %0, hwreg(20, 0, 32)" : "=s"(myxcd));   // HW_REG_XCC_ID
  myxcd &= 7;
  unsigned* larrp  = bar + myxcd * 64;          // per-XCD arrive ctr (L2-local)
  unsigned* gbarp  = bar + 512;                 // global arrive ctr (MALL)
  unsigned* gflagp = bar + 544;                 // global release flag (MALL)

  // ---- preload B into LDS in MFMA-fragment order (R6/R10-verified) ----
  // 16B unit (g*32+c)*64+l holds W[g*1024+col0+(l&15)][c*32+(l>>4)*8 ..+8]
  const bf16* Wsrc = (role == 0) ? Wh0 : ((role == 1) ? Wi1 : Wh1);
#pragma unroll
  for (int it = 0; it < 12; ++it) {
    const int u0 = it * 512 + (tid & ~63);      // wave-uniform LDS unit base
    const int u  = u0 + lane;
    const int g  = u >> 11, c = (u >> 6) & 31, l = u & 63;
    gl_lds16(Wsrc + ((size_t)(g * Hn + col0 + (l & 15))) * Hn + c * 32 + (l >> 4) * 8,
             smem + (size_t)u0 * 16);
  }

  f32x4 hreg[4] = {};
  float bv[3] = {};
  if (role != 1) {
    if (kq == 0) {
      const float* hsrc = hidden + (role == 2 ? BHn : 0);
#pragma unroll
      for (int rt = 0; rt < 4; ++rt)
#pragma unroll
        for (int r = 0; r < 4; ++r)
          hreg[rt][r] = hsrc[(size_t)(mh * 64 + rt * 16 + lk * 4 + r) * Hn + col];
    }
  } else {
#pragma unroll
    for (int g = 0; g < 3; ++g) bv[g] = b1[g * Hn + col];
  }
  asm volatile("s_waitcnt vmcnt(0)" ::: "memory");
  __syncthreads();

  // ---- init barrier: learn this XCD's block count (R6-verified) ----
  unsigned perxcd = 0;
  if (tid == 0) {
    (void)__hip_atomic_fetch_add(larrp, 1u, __ATOMIC_RELAXED, __HIP_MEMORY_SCOPE_WORKGROUP);
    asm volatile("s_waitcnt vmcnt(0)" ::: "memory");
    unsigned g = __hip_atomic_fetch_add(gbarp, 1u, __ATOMIC_RELAXED, __HIP_MEMORY_SCOPE_AGENT);
    if (g == NBLK - 1)
      __hip_atomic_store(gflagp, 1u, __ATOMIC_RELAXED, __HIP_MEMORY_SCOPE_AGENT);
    while (__hip_atomic_load(gflagp, __ATOMIC_RELAXED, __HIP_MEMORY_SCOPE_AGENT) < 1u)
      __builtin_amdgcn_s_sleep(2);
    perxcd = __hip_atomic_fetch_add(larrp, 0u, __ATOMIC_RELAXED, __HIP_MEMORY_SCOPE_WORKGROUP);
  }
  __syncthreads();

  char* zA = smem + 98304 + (size_t)(mh * 2 + 0) * 12288;
  char* zB = smem + 98304 + (size_t)(mh * 2 + 1) * 12288;

  for (int s = 0; s < 72; ++s) {
    const int t = s - role;
    if (t >= 0 && t < SEQn) {
      const bf16* Asrc = (role == 0) ? (ys0 + (size_t)t * BHn)
                       : (role == 1) ? (ys0 + (size_t)(t + 1) * BHn)
                                     : (ys1 + (size_t)t * BHn);
      const bf16* pA[4];
#pragma unroll
      for (int rt = 0; rt < 4; ++rt)
        pA[rt] = Asrc + (size_t)(mh * 64 + rt * 16 + lr) * Hn + kq * 256 + lk * 8;

      f32x4 acc[4][3] = {};
      short8 a0[4], a1[4], b0[3], b1f[3];
      LDB(b0, 0)  LDA(a0, 0)
      LDB(b1f, 1) LDA(a1, 1)
      MF(a0, b0)  LDB(b0, 2)  LDA(a0, 2)
      MF(a1, b1f) LDB(b1f, 3) LDA(a1, 3)
      MF(a0, b0)  LDB(b0, 4)  LDA(a0, 4)
      MF(a1, b1f) LDB(b1f, 5) LDA(a1, 5)
      MF(a0, b0)  LDB(b0, 6)  LDA(a0, 6)
      MF(a1, b1f) LDB(b1f, 7) LDA(a1, 7)
      MF(a0, b0)
      MF(a1, b1f)

      // ---- cross-kq reduction, 2 rounds via 4 zones ----
      if (kq == 1) { WRZ(zA) }
      if (kq == 3) { WRZ(zB) }
      __syncthreads();
      if (kq == 0) { ADDZ(zA) }
      if (kq == 2) { ADDZ(zB) WRZ(zB) }
      __syncthreads();
      if (kq == 0) { ADDZ(zB) }

      // ---- epilogue (kq==0 waves: mh 0 -> rows 0..63, mh 1 -> 64..127) ----
      if (kq == 0) {
        if (role == 1) {
#pragma unroll
          for (int rt = 0; rt < 4; ++rt)
#pragma unroll
            for (int g = 0; g < 3; ++g)
#pragma unroll
              for (int r = 0; r < 4; ++r) {
                const int row = mh * 64 + rt * 16 + lk * 4 + r;
                unsigned short v = __builtin_bit_cast(unsigned short,
                                                      f2bf(acc[rt][g][r] + bv[g]));
                __hip_atomic_store(
                    (unsigned short*)&xg[((size_t)t * Bn + row) * H3n + g * Hn + col],
                    v, __ATOMIC_RELAXED, __HIP_MEMORY_SCOPE_AGENT);
              }
        } else {
          const bf16* xsrc = xg + (size_t)t * Bn * (size_t)H3n;
          bf16* ydst = ((role == 0) ? ys0 : ys1) + (size_t)(t + 1) * BHn;
          float* hTd = hT + (role == 0 ? 0 : BHn);
#pragma unroll
          for (int rt = 0; rt < 4; ++rt)
#pragma unroll
            for (int r = 0; r < 4; ++r) {
              const int row = mh * 64 + rt * 16 + lk * 4 + r;
              const unsigned short* px =
                  (const unsigned short*)(xsrc + (size_t)row * H3n + col);
              unsigned short uxr, uxz, uxh;
              if (role == 2) {
                uxr = __hip_atomic_load((unsigned short*)px, __ATOMIC_RELAXED, __HIP_MEMORY_SCOPE_AGENT);
                uxz = __hip_atomic_load((unsigned short*)(px + Hn), __ATOMIC_RELAXED, __HIP_MEMORY_SCOPE_AGENT);
                uxh = __hip_atomic_load((unsigned short*)(px + 2 * Hn), __ATOMIC_RELAXED, __HIP_MEMORY_SCOPE_AGENT);
              } else {
                uxr = px[0]; uxz = px[Hn]; uxh = px[2 * Hn];
              }
              const float xr = bf2f(__builtin_bit_cast(bf16, uxr));
              const float xz = bf2f(__builtin_bit_cast(bf16, uxz));
              const float xh = bf2f(__builtin_bit_cast(bf16, uxh));
              const float rg = 1.f / (1.f + __expf(-(xr + acc[rt][0][r])));
              const float zg = 1.f / (1.f + __expf(-(xz + acc[rt][1][r])));
              const float hc = tanhf(xh + rg * acc[rt][2][r]);
              const float hn = (1.f - zg) * hc + zg * hreg[rt][r];
              hreg[rt][r] = hn;
              unsigned short v = __builtin_bit_cast(unsigned short, f2bf(hn));
              __hip_atomic_store((unsigned short*)&ydst[(size_t)row * Hn + col],
                                 v, __ATOMIC_RELAXED, __HIP_MEMORY_SCOPE_AGENT);
              if (t == SEQn - 1) hTd[(size_t)row * Hn + col] = hn;
            }
        }
      }
    }
    // ---- hierarchical grid barrier (R6-verified, all tid0 poll MALL flag) ----
    if (s < 71) {
      __syncthreads();    // per-wave vmcnt(0) drain before s_barrier
      if (tid == 0) {
        unsigned a = __hip_atomic_fetch_add(larrp, 1u, __ATOMIC_RELAXED,
                                            __HIP_MEMORY_SCOPE_WORKGROUP);
        if (a == perxcd * (unsigned)(s + 2) - 1u) {            // XCD-last this stage
          unsigned g = __hip_atomic_fetch_add(gbarp, perxcd, __ATOMIC_RELAXED,
                                              __HIP_MEMORY_SCOPE_AGENT);
          if (g + perxcd == (unsigned)NBLK * (unsigned)(s + 2))   // device-last
            __hip_atomic_store(gflagp, (unsigned)(s + 2), __ATOMIC_RELAXED,
                               __HIP_MEMORY_SCOPE_AGENT);
        }
        while (__hip_atomic_load(gflagp, __ATOMIC_RELAXED,
                                 __HIP_MEMORY_SCOPE_AGENT) < (unsigned)(s + 2))
          __builtin_amdgcn_s_sleep(2);
      }
      __syncthreads();
    }
  }
}

// ---------------- launch ----------------

extern "C" void kernel_launch(void* const* d_in, const int* in_sizes, int n_in,
                              void* d_out, int out_size, void* d_ws, size_t ws_size,
                              hipStream_t stream)
{
  (void)in_sizes; (void)n_in; (void)out_size; (void)ws_size;
  const int*   inp    = (const int*)d_in[0];
  const float* hidden = (const float*)d_in[1];
  const float* embW   = (const float*)d_in[2];
  const float* outW   = (const float*)d_in[3];
  const float* outb   = (const float*)d_in[4];

  char* p = (char*)d_ws;
  auto take = [&](size_t n){ char* q = p; p += (n + 255) & ~(size_t)255; return q; };
  bf16*  l0Wi = (bf16*) take((size_t)H3n*En*2);
  bf16*  l0Wh = (bf16*) take((size_t)H3n*Hn*2);
  bf16*  l1Wi = (bf16*) take((size_t)H3n*Hn*2);
  bf16*  l1Wh = (bf16*) take((size_t)H3n*Hn*2);
  bf16*  oW   = (bf16*) take((size_t)VPADn*Hn*2);
  float* b0   = (float*)take((size_t)H3n*4);
  float* b1   = (float*)take((size_t)H3n*4);
  bf16*  emb  = (bf16*) take((size_t)Mn*En*2);
  bf16*  xg   = (bf16*) take((size_t)Mn*H3n*2);
  bf16*  ys0  = (bf16*) take((size_t)(SEQn+1)*BHn*2);
  bf16*  ys1  = (bf16*) take((size_t)(SEQn+1)*BHn*2);
  unsigned* bar = (unsigned*)take(4096);

  // weight/bias prep (bf16, gate-concatenated [r;z;h])
  cat3_w<<<dim3((3*Hn*En+255)/256),256,0,stream>>>((const float*)d_in[5],(const float*)d_in[6],(const float*)d_in[7], l0Wi, Hn*En);
  cat3_w<<<dim3((3*Hn*Hn+255)/256),256,0,stream>>>((const float*)d_in[8],(const float*)d_in[9],(const float*)d_in[10], l0Wh, Hn*Hn);
  cat3_w<<<dim3((3*Hn*Hn+255)/256),256,0,stream>>>((const float*)d_in[14],(const float*)d_in[15],(const float*)d_in[16], l1Wi, Hn*Hn);
  cat3_w<<<dim3((3*Hn*Hn+255)/256),256,0,stream>>>((const float*)d_in[17],(const float*)d_in[18],(const float*)d_in[19], l1Wh, Hn*Hn);
  conv_outw<<<dim3((unsigned)(((long)VPADn*Hn+255)/256)),256,0,stream>>>(outW, oW);
  cat3_f<<<dim3((H3n+255)/256),256,0,stream>>>((const float*)d_in[11],(const float*)d_in[12],(const float*)d_in[13], b0, Hn);
  cat3_f<<<dim3((H3n+255)/256),256,0,stream>>>((const float*)d_in[20],(const float*)d_in[21],(const float*)d_in[22], b1, Hn);
  f2b_k<<<dim3((BHn+255)/256),256,0,stream>>>(hidden, ys0, BHn);          // ys0 slot 0 = h0 init
  f2b_k<<<dim3((BHn+255)/256),256,0,stream>>>(hidden + BHn, ys1, BHn);    // ys1 slot 0 = h1 init
  embed_k<<<dim3(Mn),256,0,stream>>>(inp, embW, emb);
  (void)hipMemsetAsync(bar, 0, 4096, stream);

  // layer-0 input projection (xg slots hold xg0; role 1 overwrites per-stage)
  gemm_bt<true,false><<<dim3(H3n/128, Mn/128),256,0,stream>>>(emb, l0Wi, b0, xg, En, H3n, H3n);

  // both recurrences + layer-1 input projection, fully pipelined
  float* hT = (float*)d_out + (size_t)SEQn * Bn * Vn;
  gru_persist<<<dim3(NBLK), 512, 0, stream>>>(l0Wh, l1Wi, l1Wh, b1, hidden,
                                              xg, ys0, ys1, hT, bar);

  // logits: ys1 slots 1..70 are h1[0..69]
  gemm_bt<false,true><<<dim3(VPADn/128, Mn/128),256,0,stream>>>(ys1 + BHn, oW, outb, d_out, Hn, Vn, Vn);
}

// Round 13
// 1127.171 us; speedup vs baseline: 2.0976x; 1.4195x over previous
//
#include <hip/hip_runtime.h>
#include <hip/hip_bf16.h>

#define SEQn 70
#define Bn 128
#define En 512
#define Hn 1024
#define Vn 10000
#define VPADn 10240
#define Mn (SEQn*Bn)      // 8960
#define H3n (3*Hn)        // 3072
#define BHn (Bn*Hn)       // 131072
#define NBLK 192

typedef __hip_bfloat16 bf16;
typedef __attribute__((ext_vector_type(8))) short short8;
typedef __attribute__((ext_vector_type(4))) float f32x4;

__device__ __forceinline__ bf16 f2bf(float x){ return __float2bfloat16(x); }
__device__ __forceinline__ float bf2f(bf16 x){ return __bfloat162float(x); }

__device__ __forceinline__ void gl_lds16(const void* g, void* l){
  __builtin_amdgcn_global_load_lds((const __attribute__((address_space(1))) unsigned int*)g,
                                   (__attribute__((address_space(3))) unsigned int*)l, 16, 0, 0);
}

// ---------------- small prep kernels ----------------

__global__ void cat3_w(const float* __restrict__ a, const float* __restrict__ b,
                       const float* __restrict__ c, bf16* __restrict__ d, int n){
  int i = blockIdx.x * 256 + threadIdx.x;
  if (i >= 3*n) return;
  const float* s = (i < n) ? a : ((i < 2*n) ? b : c);
  int off = (i < n) ? i : ((i < 2*n) ? i - n : i - 2*n);
  d[i] = f2bf(s[off]);
}

__global__ void cat3_f(const float* __restrict__ a, const float* __restrict__ b,
                       const float* __restrict__ c, float* __restrict__ d, int n){
  int i = blockIdx.x * 256 + threadIdx.x;
  if (i >= 3*n) return;
  d[i] = (i < n) ? a[i] : ((i < 2*n) ? b[i - n] : c[i - 2*n]);
}

__global__ void f2b_k(const float* __restrict__ s, bf16* __restrict__ d, int n){
  int i = blockIdx.x * 256 + threadIdx.x;
  if (i < n) d[i] = f2bf(s[i]);
}

__global__ void conv_outw(const float* __restrict__ s, bf16* __restrict__ d){
  long i = (long)blockIdx.x * 256 + threadIdx.x;
  if (i >= (long)VPADn * Hn) return;
  int row = (int)(i >> 10);
  d[i] = (row < Vn) ? f2bf(s[i]) : f2bf(0.f);
}

__global__ void embed_k(const int* __restrict__ idx, const float* __restrict__ eW,
                        bf16* __restrict__ out){
  const int sb = blockIdx.x;
  const int t = idx[sb];
  const float* s = eW + (long)t * En;
  bf16* d = out + (long)sb * En;
  for (int e = threadIdx.x; e < En; e += 256) d[e] = f2bf(s[e]);
}

// ---------------- GEMM: C[M,N] = A[M,K] * B[N,K]^T + bias ----------------

template<bool OB, bool NB>
__global__ __launch_bounds__(256)
void gemm_bt(const bf16* __restrict__ A, const bf16* __restrict__ Bm,
             const float* __restrict__ bias, void* __restrict__ C,
             int K, int ldc, int nvalid)
{
  __shared__ __align__(16) bf16 As[128*64];
  __shared__ __align__(16) bf16 Bs[128*64];
  const int tid = threadIdx.x;
  const int l = tid & 63, w = tid >> 6;
  const int lr = l & 15, lk = l >> 4;
  const int wm = (w >> 1) * 64, wn = (w & 1) * 64;
  const int mt = blockIdx.y, nt = blockIdx.x;
  const bf16* Ag = A + (long)mt * 128 * K;
  const bf16* Bg = Bm + (long)nt * 128 * K;

  f32x4 acc[4][4] = {};

  for (int kb = 0; kb < K; kb += 64) {
#pragma unroll
    for (int r = 0; r < 4; ++r) {
      const int u = r * 256 + tid;
      const int row = u >> 3, kus = (u & 7) ^ (row & 7);
      gl_lds16(Ag + (long)row * K + kb + kus * 8, (char*)As + (r * 256 + w * 64) * 16);
    }
#pragma unroll
    for (int r = 0; r < 4; ++r) {
      const int u = r * 256 + tid;
      const int row = u >> 3, kus = (u & 7) ^ (row & 7);
      gl_lds16(Bg + (long)row * K + kb + kus * 8, (char*)Bs + (r * 256 + w * 64) * 16);
    }
    __syncthreads();
#pragma unroll
    for (int kh = 0; kh < 2; ++kh) {
      const int ku = kh * 4 + lk;
      short8 af[4], bfv[4];
#pragma unroll
      for (int i = 0; i < 4; ++i) {
        const int ar = wm + i * 16 + lr;
        af[i]  = *(const short8*)((const char*)As + ar * 128 + ((ku ^ (ar & 7)) * 16));
        const int br = wn + i * 16 + lr;
        bfv[i] = *(const short8*)((const char*)Bs + br * 128 + ((ku ^ (br & 7)) * 16));
      }
#pragma unroll
      for (int i = 0; i < 4; ++i)
#pragma unroll
        for (int j = 0; j < 4; ++j)
          acc[i][j] = __builtin_amdgcn_mfma_f32_16x16x32_bf16(af[i], bfv[j], acc[i][j], 0, 0, 0);
    }
    __syncthreads();
  }

#pragma unroll
  for (int i = 0; i < 4; ++i) {
#pragma unroll
    for (int j = 0; j < 4; ++j) {
      const int col = nt * 128 + wn + j * 16 + lr;
      const bool cok = (!NB) || (col < nvalid);
      const float bv = cok ? bias[col] : 0.f;
      const int row = mt * 128 + wm + i * 16 + lk * 4;
      if (cok) {
#pragma unroll
        for (int r = 0; r < 4; ++r) {
          const float v = acc[i][j][r] + bv;
          if (OB) ((bf16*)C)[(long)(row + r) * ldc + col] = f2bf(v);
          else    ((float*)C)[(long)(row + r) * ldc + col] = v;
        }
      }
    }
  }
}

// ---------------- elastic 3-domain persistent GRU ----------------
// 192 blocks x 256 threads (4 waves) = R6's verified compute core (843us):
// weights LDS-resident in MFMA-fragment order (conflict-free base+lane*16),
// M-rep=2 (each B-frag read feeds 2 MFMAs), full K per wave, xg prefetch
// overlapped under the MFMA chain, in-wave epilogue, h-carry in registers.
// NEW: per-role sync domains instead of one 192-block lockstep barrier.
// True deps (iter = 0..69 per role):
//   role0 iter t: own-role barrier (F0>=t). reads ys0[t], xg[t]; writes ys0[t+1].
//   role1 iter u: F0>=u+1 (ys0[u+1] ready AND role0 done reading xg[u]).
//                 reads ys0[u+1]; overwrites xg[u].
//   role2 iter v: F1>=v+1 (xg[v] rewritten) + F2>=v (own ys1[v] ready).
//                 reads ys1[v], xg[v] (agent); writes ys1[v+1].
// Arrive: hierarchical per role (per-XCD L2 RMW -> leader MALL RMW ->
// device-last publishes F_role = iters_done, agent store). All cross-block
// polls use AGENT-scope loads (R6-verified; R11's workgroup-scope poll
// deadlocked). Steady state: cross-role polls return instantly; only the
// 64-block own-role barrier costs time; stragglers don't propagate.

#define LDGRP(bb, aa, cbase)                                                   \
  _Pragma("unroll")                                                            \
  for (int g = 0; g < 3; ++g)                                                  \
    _Pragma("unroll")                                                          \
    for (int j = 0; j < 4; ++j)                                                \
      bb[g][j] = *(const short8*)(smem +                                       \
          ((size_t)((g * 32 + (cbase) + j) * 64 + lane)) * 16);                \
  _Pragma("unroll")                                                            \
  for (int rt = 0; rt < 2; ++rt)                                               \
    _Pragma("unroll")                                                          \
    for (int j = 0; j < 4; ++j)                                                \
      aa[rt][j] = *(const short8*)(Arow[rt] + ((cbase) + j) * 32 + lk * 8);

#define MFGRP(bb, aa)                                                          \
  _Pragma("unroll")                                                            \
  for (int j = 0; j < 4; ++j)                                                  \
    _Pragma("unroll")                                                          \
    for (int rt = 0; rt < 2; ++rt)                                             \
      _Pragma("unroll")                                                        \
      for (int g = 0; g < 3; ++g)                                              \
        acc[rt][g] = __builtin_amdgcn_mfma_f32_16x16x32_bf16(                  \
            aa[rt][j], bb[g][j], acc[rt][g], 0, 0, 0);

__global__ __launch_bounds__(256, 1)
void gru_persist(const bf16* __restrict__ Wh0, const bf16* __restrict__ Wi1,
                 const bf16* __restrict__ Wh1, const float* __restrict__ b1,
                 const float* __restrict__ hidden, bf16* __restrict__ xg,
                 bf16* __restrict__ ys0, bf16* __restrict__ ys1,
                 float* __restrict__ hT, unsigned* __restrict__ bar)
{
  __shared__ __align__(16) char smem[98304];   // 6144 16B units, fragment order

  const int tid = threadIdx.x;
  const int lane = tid & 63, wid = tid >> 6;   // wid 0..3
  const int wbase = tid & ~63;
  const int lr = lane & 15, lk = lane >> 4;
  const int role = blockIdx.x >> 6, nb = blockIdx.x & 63;
  const int col0 = nb * 16;
  const int col = col0 + lr;

  unsigned myxcd;
  asm("s_getreg_b32 %0, hwreg(20, 0, 32)" : "=s"(myxcd));   // HW_REG_XCC_ID
  myxcd &= 7;
  // bar layout (ints, 128B-spaced): [ (role*8+xcd)*32 ] local arrive (L2-local)
  //   768 Ginit | 800 Finit | 832+r*32 G[r] (MALL) | 928+r*32 F[r] (MALL)
  unsigned* Lp = bar + (role * 8 + (int)myxcd) * 32;
  unsigned* Gi = bar + 768;
  unsigned* Fi = bar + 800;
  unsigned* Gr = bar + 832 + role * 32;
  unsigned* Fr = bar + 928 + role * 32;
  unsigned* Fdep = bar + 928 + (role - 1) * 32;   // role1 -> F0, role2 -> F1

  // ---- preload weights into LDS in MFMA-fragment order (R6-verified) ----
  // 16B unit (g*32+c)*64+l holds W[g*1024+col0+(l&15)][c*32+(l>>4)*8 ..+8]
  const bf16* Wsrc = (role == 0) ? Wh0 : ((role == 1) ? Wi1 : Wh1);
#pragma unroll
  for (int it = 0; it < 24; ++it) {
    const int u0 = it * 256 + wbase;           // wave-uniform LDS unit base
    const int u  = u0 + lane;
    const int g  = u >> 11, c = (u >> 6) & 31, l = u & 63;
    gl_lds16(Wsrc + ((size_t)(g * Hn + col0 + (l & 15))) * Hn + c * 32 + (l >> 4) * 8,
             smem + (size_t)u0 * 16);
  }

  f32x4 hreg[2] = {};
  float bv[3] = {};
  if (role != 1) {
    const float* hsrc = hidden + (role == 2 ? BHn : 0);
#pragma unroll
    for (int rt = 0; rt < 2; ++rt)
#pragma unroll
      for (int r = 0; r < 4; ++r)
        hreg[rt][r] = hsrc[(size_t)((2 * wid + rt) * 16 + lk * 4 + r) * Hn + col];
  } else {
#pragma unroll
    for (int g = 0; g < 3; ++g) bv[g] = b1[g * Hn + col];
  }
  asm volatile("s_waitcnt vmcnt(0)" ::: "memory");
  __syncthreads();

  // ---- init barrier (all 192): learn this role's block count on this XCD ----
  unsigned perxcd = 0;
  if (tid == 0) {
    (void)__hip_atomic_fetch_add(Lp, 1u, __ATOMIC_RELAXED, __HIP_MEMORY_SCOPE_WORKGROUP);
    asm volatile("s_waitcnt vmcnt(0)" ::: "memory");
    unsigned g = __hip_atomic_fetch_add(Gi, 1u, __ATOMIC_RELAXED, __HIP_MEMORY_SCOPE_AGENT);
    if (g == NBLK - 1)
      __hip_atomic_store(Fi, 1u, __ATOMIC_RELAXED, __HIP_MEMORY_SCOPE_AGENT);
    while (__hip_atomic_load(Fi, __ATOMIC_RELAXED, __HIP_MEMORY_SCOPE_AGENT) < 1u)
      __builtin_amdgcn_s_sleep(2);
    perxcd = __hip_atomic_fetch_add(Lp, 0u, __ATOMIC_RELAXED, __HIP_MEMORY_SCOPE_WORKGROUP);
  }
  __syncthreads();

  for (int t = 0; t < SEQn; ++t) {
    // ---- start-wait: only the true dependencies ----
    if (tid == 0) {
      if (role == 0) {
        while (__hip_atomic_load(Fr, __ATOMIC_RELAXED, __HIP_MEMORY_SCOPE_AGENT) < (unsigned)t)
          __builtin_amdgcn_s_sleep(1);
      } else if (role == 1) {
        while (__hip_atomic_load(Fdep, __ATOMIC_RELAXED, __HIP_MEMORY_SCOPE_AGENT) < (unsigned)(t + 1))
          __builtin_amdgcn_s_sleep(1);
      } else {
        while (__hip_atomic_load(Fdep, __ATOMIC_RELAXED, __HIP_MEMORY_SCOPE_AGENT) < (unsigned)(t + 1))
          __builtin_amdgcn_s_sleep(1);
        while (__hip_atomic_load(Fr, __ATOMIC_RELAXED, __HIP_MEMORY_SCOPE_AGENT) < (unsigned)t)
          __builtin_amdgcn_s_sleep(1);
      }
    }
    __syncthreads();

    const bf16* Asrc = (role == 0) ? (ys0 + (size_t)t * BHn)
                     : (role == 1) ? (ys0 + (size_t)(t + 1) * BHn)
                                   : (ys1 + (size_t)t * BHn);
    const bf16* Arow[2];
    Arow[0] = Asrc + (size_t)((2 * wid) * 16 + lr) * Hn;
    Arow[1] = Asrc + (size_t)((2 * wid + 1) * 16 + lr) * Hn;
    f32x4 acc[2][3] = {};
    short8 bA[3][4], bB[3][4], aA[2][4], aB[2][4];
    unsigned short xus[2][12];

    LDGRP(bA, aA, 0)
    LDGRP(bB, aB, 4)
    if (role != 1) {
      // prefetch the xg slice now; latency hides under the MFMA chain
      const bf16* xsrc = xg + (size_t)t * Bn * (size_t)H3n;
#pragma unroll
      for (int rt = 0; rt < 2; ++rt)
#pragma unroll
        for (int g = 0; g < 3; ++g)
#pragma unroll
          for (int r = 0; r < 4; ++r) {
            const int row = (2 * wid + rt) * 16 + lk * 4 + r;
            const unsigned short* p =
                (const unsigned short*)(xsrc + (size_t)row * H3n + g * Hn + col);
            xus[rt][g * 4 + r] = (role == 2)
              ? __hip_atomic_load((unsigned short*)p, __ATOMIC_RELAXED, __HIP_MEMORY_SCOPE_AGENT)
              : *p;
          }
    }
    MFGRP(bA, aA) LDGRP(bA, aA, 8)
    MFGRP(bB, aB) LDGRP(bB, aB, 12)
    MFGRP(bA, aA) LDGRP(bA, aA, 16)
    MFGRP(bB, aB) LDGRP(bB, aB, 20)
    MFGRP(bA, aA) LDGRP(bA, aA, 24)
    MFGRP(bB, aB) LDGRP(bB, aB, 28)
    MFGRP(bA, aA)
    MFGRP(bB, aB)

    // ---- epilogue (in-wave; R6-verified) ----
    if (role == 1) {
#pragma unroll
      for (int rt = 0; rt < 2; ++rt)
#pragma unroll
        for (int g = 0; g < 3; ++g)
#pragma unroll
          for (int r = 0; r < 4; ++r) {
            const int row = (2 * wid + rt) * 16 + lk * 4 + r;
            unsigned short v = __builtin_bit_cast(unsigned short,
                                                  f2bf(acc[rt][g][r] + bv[g]));
            __hip_atomic_store(
                (unsigned short*)&xg[((size_t)t * Bn + row) * H3n + g * Hn + col],
                v, __ATOMIC_RELAXED, __HIP_MEMORY_SCOPE_AGENT);
          }
    } else {
      bf16* ydst = ((role == 0) ? ys0 : ys1) + (size_t)(t + 1) * BHn;
#pragma unroll
      for (int rt = 0; rt < 2; ++rt)
#pragma unroll
        for (int r = 0; r < 4; ++r) {
          const int row = (2 * wid + rt) * 16 + lk * 4 + r;
          const float xr = bf2f(__builtin_bit_cast(bf16, xus[rt][r]));
          const float xz = bf2f(__builtin_bit_cast(bf16, xus[rt][4 + r]));
          const float xh = bf2f(__builtin_bit_cast(bf16, xus[rt][8 + r]));
          const float rg = 1.f / (1.f + __expf(-(xr + acc[rt][0][r])));
          const float zg = 1.f / (1.f + __expf(-(xz + acc[rt][1][r])));
          const float hc = tanhf(xh + rg * acc[rt][2][r]);
          const float hn = (1.f - zg) * hc + zg * hreg[rt][r];
          hreg[rt][r] = hn;
          unsigned short v = __builtin_bit_cast(unsigned short, f2bf(hn));
          __hip_atomic_store((unsigned short*)&ydst[(size_t)row * Hn + col],
                             v, __ATOMIC_RELAXED, __HIP_MEMORY_SCOPE_AGENT);
          if (t == SEQn - 1)
            hT[(role == 0 ? 0 : BHn) + (size_t)row * Hn + col] = hn;
        }
    }

    // ---- end-arrive: own-role hierarchical (no polling here) ----
    __syncthreads();   // drains all waves' stores (vmcnt 0) before arrive
    if (tid == 0) {
      unsigned a = __hip_atomic_fetch_add(Lp, 1u, __ATOMIC_RELAXED,
                                          __HIP_MEMORY_SCOPE_WORKGROUP);
      if (a == perxcd * (unsigned)(t + 2) - 1u) {              // XCD-last (this role)
        unsigned g = __hip_atomic_fetch_add(Gr, perxcd, __ATOMIC_RELAXED,
                                            __HIP_MEMORY_SCOPE_AGENT);
        if (g + perxcd == 64u * (unsigned)(t + 1))             // role-last
          __hip_atomic_store(Fr, (unsigned)(t + 1), __ATOMIC_RELAXED,
                             __HIP_MEMORY_SCOPE_AGENT);
      }
    }
  }
}

// ---------------- launch ----------------

extern "C" void kernel_launch(void* const* d_in, const int* in_sizes, int n_in,
                              void* d_out, int out_size, void* d_ws, size_t ws_size,
                              hipStream_t stream)
{
  (void)in_sizes; (void)n_in; (void)out_size; (void)ws_size;
  const int*   inp    = (const int*)d_in[0];
  const float* hidden = (const float*)d_in[1];
  const float* embW   = (const float*)d_in[2];
  const float* outW   = (const float*)d_in[3];
  const float* outb   = (const float*)d_in[4];

  char* p = (char*)d_ws;
  auto take = [&](size_t n){ char* q = p; p += (n + 255) & ~(size_t)255; return q; };
  bf16*  l0Wi = (bf16*) take((size_t)H3n*En*2);
  bf16*  l0Wh = (bf16*) take((size_t)H3n*Hn*2);
  bf16*  l1Wi = (bf16*) take((size_t)H3n*Hn*2);
  bf16*  l1Wh = (bf16*) take((size_t)H3n*Hn*2);
  bf16*  oW   = (bf16*) take((size_t)VPADn*Hn*2);
  float* b0   = (float*)take((size_t)H3n*4);
  float* b1   = (float*)take((size_t)H3n*4);
  bf16*  emb  = (bf16*) take((size_t)Mn*En*2);
  bf16*  xg   = (bf16*) take((size_t)Mn*H3n*2);
  bf16*  ys0  = (bf16*) take((size_t)(SEQn+1)*BHn*2);
  bf16*  ys1  = (bf16*) take((size_t)(SEQn+1)*BHn*2);
  unsigned* bar = (unsigned*)take(4096);

  // weight/bias prep (bf16, gate-concatenated [r;z;h])
  cat3_w<<<dim3((3*Hn*En+255)/256),256,0,stream>>>((const float*)d_in[5],(const float*)d_in[6],(const float*)d_in[7], l0Wi, Hn*En);
  cat3_w<<<dim3((3*Hn*Hn+255)/256),256,0,stream>>>((const float*)d_in[8],(const float*)d_in[9],(const float*)d_in[10], l0Wh, Hn*Hn);
  cat3_w<<<dim3((3*Hn*Hn+255)/256),256,0,stream>>>((const float*)d_in[14],(const float*)d_in[15],(const float*)d_in[16], l1Wi, Hn*Hn);
  cat3_w<<<dim3((3*Hn*Hn+255)/256),256,0,stream>>>((const float*)d_in[17],(const float*)d_in[18],(const float*)d_in[19], l1Wh, Hn*Hn);
  conv_outw<<<dim3((unsigned)(((long)VPADn*Hn+255)/256)),256,0,stream>>>(outW, oW);
  cat3_f<<<dim3((H3n+255)/256),256,0,stream>>>((const float*)d_in[11],(const float*)d_in[12],(const float*)d_in[13], b0, Hn);
  cat3_f<<<dim3((H3n+255)/256),256,0,stream>>>((const float*)d_in[20],(const float*)d_in[21],(const float*)d_in[22], b1, Hn);
  f2b_k<<<dim3((BHn+255)/256),256,0,stream>>>(hidden, ys0, BHn);          // ys0 slot 0 = h0 init
  f2b_k<<<dim3((BHn+255)/256),256,0,stream>>>(hidden + BHn, ys1, BHn);    // ys1 slot 0 = h1 init
  embed_k<<<dim3(Mn),256,0,stream>>>(inp, embW, emb);
  (void)hipMemsetAsync(bar, 0, 4096, stream);

  // layer-0 input projection (xg slots hold xg0; role 1 overwrites per-iter)
  gemm_bt<true,false><<<dim3(H3n/128, Mn/128),256,0,stream>>>(emb, l0Wi, b0, xg, En, H3n, H3n);

  // both recurrences + layer-1 input projection, elastically pipelined
  float* hT = (float*)d_out + (size_t)SEQn * Bn * Vn;
  gru_persist<<<dim3(NBLK), 256, 0, stream>>>(l0Wh, l1Wi, l1Wh, b1, hidden,
                                              xg, ys0, ys1, hT, bar);

  // logits: ys1 slots 1..70 are h1[0..69]
  gemm_bt<false,true><<<dim3(VPADn/128, Mn/128),256,0,stream>>>(ys1 + BHn, oW, outb, d_out, Hn, Vn, Vn);
}